// Round 9
// baseline (109.718 us; speedup 1.0000x reference)
//
#include <hip/hip_runtime.h>

// ---------------------------------------------------------------------------
// 9-qubit batched state-vector simulator, v9.
//  - v6/v8 structure: fp32 b64 staging, XOR swizzle, 1 elem/wave, no barrier.
//  - FIX: gate {c,s} pairs scoped PER LAYER (9 pairs = 18 SGPRs) — v8's
//    27-pair whole-kernel hoist didn't fit (SGPR=64 cap) so the compiler
//    kept scattering s_loads+waits through the gate stream.
//  - gates as in-place VOP3P asm (4 ops/pair, 1 temp, "+v" — no copy movs).
//  - epilogue pk-ified: packed signed accumulation + packed FWHT.
// ---------------------------------------------------------------------------

typedef float v2f __attribute__((ext_vector_type(2)));

constexpr int pf(int l, int i) {        // forward CNOT-ring basis map, layer l
    const int r = l + 1; int j = i;
    for (int c = 0; c < 9; ++c) {
        const int bit = (j >> (8 - c)) & 1;
        const int t = (c + r) % 9;
        j ^= bit << (8 - t);
    }
    return j;
}
constexpr int sg(int i) { return i ^ (i >> 4); }   // LDS anti-conflict swizzle

struct PMask { int m[2][9]; };
constexpr PMask make_pmask() {
    PMask pm{};
    for (int bd = 0; bd < 2; ++bd)
        for (int q = 0; q < 9; ++q) {
            const int img = pf(bd, 1 << q);
            for (int p = 0; p < 9; ++p)
                if ((img >> p) & 1) pm.m[bd][p] |= 1 << q;
        }
    return pm;
}
constexpr PMask PM = make_pmask();

struct T3Tab { int laneBase[2][6]; int regPart[2][8]; };
constexpr T3Tab make_t3() {
    T3Tab t{};
    for (int l = 0; l < 2; ++l) {
        for (int b = 0; b < 6; ++b) t.laneBase[l][b] = sg(pf(l, 1 << b));
        for (int g = 0; g < 8; ++g) t.regPart [l][g] = sg(pf(l, g << 6));
    }
    return t;
}
constexpr T3Tab T3T = make_t3();

constexpr int sgk3(int k) { return (k << 3) ^ (k >> 1); }   // sg(k<<3)
constexpr int sgk6(int k) { return (k << 6) ^ (k << 2); }   // sg(k<<6)

#define PI_F    3.14159265358979323846f
#define INV2PI  0.15915494309189535f

// ws layout (floats):
//   [0..54)           gates: 27 x {c, s}   (even-aligned pairs)
//   [64..2112)        D0q: 512 float4 {dx,dx,-dy,dy}  boundary 1->2
//   [2112..4160)      D1q: 512 float4                 boundary 2->3
//   [4160..5184)      PH : 512 v2f init-state phase
__global__ __launch_bounds__(512) void qtab_kernel(
        const float* __restrict__ wt, float* __restrict__ ws) {
    const int j = threadIdx.x;             // 0..511
    if (j < 27) {
        float s, c; __sincosf(0.5f * wt[j * 3 + 1], &s, &c);
        ws[2 * j]     = c;
        ws[2 * j + 1] = s;
    }
    float4* dq = (float4*)(ws + 64);
    #pragma unroll
    for (int bd = 0; bd < 2; ++bd) {
        float alpha = 0.0f;
        #pragma unroll
        for (int p = 0; p < 9; ++p) {
            const int w = 8 - p;
            const float om = wt[(bd * 9 + w) * 3 + 2];        // omega, layer bd
            const float ph = wt[((bd + 1) * 9 + w) * 3 + 0];  // phi, layer bd+1
            alpha += ((j >> p) & 1) ? 0.5f * om : -0.5f * om;
            alpha += (__popc(j & PM.m[bd][p]) & 1) ? 0.5f * ph : -0.5f * ph;
        }
        float sn, cs; __sincosf(alpha, &sn, &cs);
        dq[bd * 512 + j] = make_float4(cs, cs, -sn, sn);
    }
    {
        float a = 0.0f;
        #pragma unroll
        for (int p = 0; p < 9; ++p) {
            const int w = 8 - p;
            const float phi = wt[w * 3 + 0];
            a += ((j >> p) & 1) ? (0.5f * phi - 0.5f * PI_F) : (-0.5f * phi);
        }
        float sn, cs; __sincosf(a, &sn, &cs);
        ((v2f*)(ws + 4160))[j] = (v2f){cs, sn};
    }
}

// packed real-Y gate, in-place, coefficients from ONE SGPR pair G={c,s}:
//   t  = -s*a1 ; a1 = c*a1 ; a1 = fma(a0,s,a1) ; a0 = fma(a0,c,t)
// (out0 = c*a0 - s*a1 ; out1 = s*a0 + c*a1, re & im packed in each v2f)
#define APPLY_GATE(G, KB)                                                     \
    {                                                                         \
        _Pragma("unroll")                                                     \
        for (int k0 = 0; k0 < 8; ++k0) if (!(k0 & (KB))) {                    \
            const int k1 = k0 | (KB);                                         \
            v2f t;                                                            \
            asm("v_pk_mul_f32 %0, %1, %2 op_sel:[0,1] op_sel_hi:[1,1] "       \
                "neg_lo:[0,1] neg_hi:[0,1]"                                   \
                : "=v"(t) : "v"(a[k1]), "s"(G));        /* t = -s*a1 */       \
            asm("v_pk_mul_f32 %0, %0, %1 op_sel:[0,0] op_sel_hi:[1,0]"        \
                : "+v"(a[k1]) : "s"(G));                /* a1 = c*a1 */       \
            asm("v_pk_fma_f32 %0, %1, %2, %0 op_sel:[0,1,0] op_sel_hi:[1,1,1]"\
                : "+v"(a[k1]) : "v"(a[k0]), "s"(G));    /* a1 += s*a0 */      \
            asm("v_pk_fma_f32 %0, %0, %1, %2 op_sel:[0,0,0] op_sel_hi:[1,0,1]"\
                : "+v"(a[k0]) : "s"(G), "v"(t));        /* a0 = c*a0+t */     \
        }                                                                     \
    }

__global__ __launch_bounds__(256) void qsim_kernel(
        const float* __restrict__ x,       // (batch, 9)
        const float* __restrict__ tab,     // ws tables
        float* __restrict__ out,           // (batch, 9)
        int batch) {
    __shared__ v2f st[4][512];             // per-wave staging (16 KiB)

    const int tid  = threadIdx.x;
    const int wv   = tid >> 6;
    const int lane = tid & 63;
    const int b    = blockIdx.x * 4 + wv;
    if (b >= batch) return;
    const int bu   = __builtin_amdgcn_readfirstlane(b);   // wave-uniform

    v2f* __restrict__ S = st[wv];
    const float4* __restrict__ D0 = (const float4*)(tab + 64);
    const float4* __restrict__ D1 = D0 + 512;
    const v2f*   __restrict__ PH = (const v2f*)(tab + 4160);

    // ---- init: magnitudes via HW trig (revolutions), phase from table ----
    float cx[9], sx[9];
    #pragma unroll
    for (int w = 0; w < 9; ++w) {
        const float rev = x[bu * 9 + w] * (0.5f * INV2PI);
        sx[w] = __builtin_amdgcn_sinf(rev);
        cx[w] = __builtin_amdgcn_cosf(rev);
    }
    float P = 1.0f;
    #pragma unroll
    for (int w = 0; w < 6; ++w)
        P *= ((lane >> (5 - w)) & 1) ? sx[w] : cx[w];

    v2f a[8];
    #pragma unroll
    for (int k = 0; k < 8; ++k) {
        const float m = P * ((k & 4) ? sx[6] : cx[6])
                          * ((k & 2) ? sx[7] : cx[7])
                          * ((k & 1) ? sx[8] : cx[8]);
        a[k] = PH[(lane << 3) | k] * m;
    }

    // ---- swizzled address bases ----
    const int baseA = (lane << 3) ^ (lane >> 1);            // sg(L<<3)
    const int hB    = ((lane & 0x38) << 3) | (lane & 7);
    const int baseB = hB ^ (hB >> 4);
    const int baseC = lane ^ (lane >> 4);
    int t3b[2];
    #pragma unroll
    for (int l = 0; l < 2; ++l) {
        int v = 0;
        #pragma unroll
        for (int bb = 0; bb < 6; ++bb)
            v ^= ((lane >> bb) & 1) ? T3T.laneBase[l][bb] : 0;
        t3b[l] = v;
    }

    // ---- 3 layers of 9 packed real-Ry gates, swizzled LDS layout cycling ----
    #pragma unroll
    for (int l = 0; l < 3; ++l) {
        // this layer's 9 {c,s} pairs -> 18 SGPRs, one wait, live only here
        v2f g[9];
        {
            const v2f* GL = (const v2f*)tab + l * 9;
            #pragma unroll
            for (int q = 0; q < 9; ++q) g[q] = GL[q];
        }

        APPLY_GATE(g[6], 4);   // layout A: reg bits = qubits 6,7,8
        APPLY_GATE(g[7], 2);
        APPLY_GATE(g[8], 1);

        #pragma unroll
        for (int k = 0; k < 8; ++k) S[baseA ^ k] = a[k];
        #pragma unroll
        for (int k = 0; k < 8; ++k) a[k] = S[baseB ^ sgk3(k)];

        APPLY_GATE(g[3], 4);   // layout B: reg bits = qubits 3,4,5
        APPLY_GATE(g[4], 2);
        APPLY_GATE(g[5], 1);

        #pragma unroll
        for (int k = 0; k < 8; ++k) S[baseB ^ sgk3(k)] = a[k];
        #pragma unroll
        for (int k = 0; k < 8; ++k) a[k] = S[baseC ^ sgk6(k)];

        APPLY_GATE(g[0], 4);   // layout C: reg bits = qubits 0,1,2
        APPLY_GATE(g[1], 2);
        APPLY_GATE(g[2], 1);

        if (l < 2) {
            // packed boundary diagonal: a' = u*{dx,dx} + swap(u)*{-dy,dy}
            const float4* __restrict__ D = (l == 0) ? D0 : D1;
            #pragma unroll
            for (int k = 0; k < 8; ++k) {
                const float4 d = D[(k << 6) | lane];
                const v2f dd = (v2f){d.x, d.y};   // {dx,dx}
                const v2f dn = (v2f){d.z, d.w};   // {-dy,dy}
                v2f t;
                asm("v_pk_mul_f32 %0, %1, %2" : "=v"(t) : "v"(a[k]), "v"(dd));
                asm("v_pk_fma_f32 %0, %1, %2, %3 op_sel:[1,0,0] op_sel_hi:[0,1,1]"
                    : "=v"(a[k]) : "v"(a[k]), "v"(dn), "v"(t));
            }
            // T3: C -> A with the CNOT-ring permutation folded in
            #pragma unroll
            for (int k = 0; k < 8; ++k)
                S[t3b[l] ^ T3T.regPart[l][k]] = a[k];
            #pragma unroll
            for (int k = 0; k < 8; ++k) a[k] = S[baseA ^ k];
        }
    }

    // ---- epilogue: packed signed accumulation + packed FWHT ----
    v2f A0 = (v2f){0.f, 0.f}, A1 = A0, A2 = A0, A3 = A0;
    #pragma unroll
    for (int k = 0; k < 8; ++k) {
        const v2f q = a[k] * a[k];         // pk mul
        A0 += q;                           // S
        A1 += (k & 4) ? -q : q;            // U4
        A2 += (k & 2) ? -q : q;            // U2
        A3 += (k & 1) ? -q : q;            // U1
    }
    v2f F01 = (v2f){A0.x + A0.y, A1.x + A1.y};   // {F_S, F_U4}
    v2f F23 = (v2f){A2.x + A2.y, A3.x + A3.y};   // {F_U2, F_U1}

    // 6-step FWHT butterfly: lane m ends with Sum_j (-1)^popc(j&m) F(j)
    #pragma unroll
    for (int d = 1; d < 64; d <<= 1) {
        const float sg1 = (lane & d) ? -1.0f : 1.0f;
        const v2f sgn = (v2f){sg1, sg1};
        v2f p01, p23;
        p01.x = __shfl_xor(F01.x, d, 64);  p01.y = __shfl_xor(F01.y, d, 64);
        p23.x = __shfl_xor(F23.x, d, 64);  p23.y = __shfl_xor(F23.y, d, 64);
        F01 = F01 * sgn + p01;
        F23 = F23 * sgn + p23;
    }
    // gather the 9 needed Walsh coefficients via LDS (reuse staging as float)
    float* Sf = (float*)S;
    Sf[2 * lane]           = F01.x;
    Sf[2 * lane + 1]       = F01.y;
    Sf[128 + 2 * lane]     = F23.x;
    Sf[128 + 2 * lane + 1] = F23.y;
    if (lane < 9) {
        const int idx = (lane == 0) ? 72  : (lane == 1) ? 36  : (lane == 2) ? 18
                      : (lane == 3) ? 65  : (lane == 4) ? 160 : (lane == 5) ? 145
                      : (lane == 6) ? 73  : (lane == 7) ? 164 : 147;
        out[bu * 9 + lane] = Sf[idx];
    }
}

extern "C" void kernel_launch(void* const* d_in, const int* in_sizes, int n_in,
                              void* d_out, int out_size, void* d_ws, size_t ws_size,
                              hipStream_t stream) {
    const float* x  = (const float*)d_in[0];   // (32768, 9) fp32
    const float* wt = (const float*)d_in[1];   // (3, 9, 3) fp32
    float* out = (float*)d_out;                // (32768, 9) fp32
    const int batch = in_sizes[0] / 9;
    float* ws = (float*)d_ws;                  // 5184 floats = 20.7 KB used

    hipLaunchKernelGGL(qtab_kernel, dim3(1), dim3(512), 0, stream, wt, ws);
    hipLaunchKernelGGL(qsim_kernel, dim3((batch + 3) / 4), dim3(256), 0, stream,
                       x, ws, out, batch);
}

// Round 10
// 103.335 us; speedup vs baseline: 1.0618x; 1.0618x over previous
//
#include <hip/hip_runtime.h>
#include <hip/hip_fp16.h>

// ---------------------------------------------------------------------------
// 9-qubit batched state-vector simulator, v10 (fp16 packed amplitude pipeline).
// KEY INSIGHT from v6-v9 plateau: v_pk_*_f32 is 4 cyc/wave64 (fp32 datapath
// limit, 157 TF) — packed fp32 saved instructions but not cycles. The gate
// math alone is ~23 us of fp32-datapath time. v_pk_fma_f16 runs at full
// 32-bit-lane rate (2 cyc) = 2x the FLOP rate -> gates drop to ~11.5 us.
//  - amplitudes: packed half2 (re,im) in ONE VGPR, end to end
//  - gates: 4 v_pk_*_f16 ops/pair, coeff half2{c,s} broadcast from ONE SGPR
//    via op_sel/neg VOP3P modifiers
//  - DS staging b32 (2 lanes/bank = conflict-free), 8 KB LDS/block
//  - boundary diag: packed-fp16 cmul (2 ops), table = 512 u32/boundary
//  - init product state + epilogue (prob accumulation, FWHT) stay fp32
// ---------------------------------------------------------------------------

typedef float v2f __attribute__((ext_vector_type(2)));

constexpr int pf(int l, int i) {        // forward CNOT-ring basis map, layer l
    const int r = l + 1; int j = i;
    for (int c = 0; c < 9; ++c) {
        const int bit = (j >> (8 - c)) & 1;
        const int t = (c + r) % 9;
        j ^= bit << (8 - t);
    }
    return j;
}
constexpr int sg(int i) { return i ^ (i >> 4); }   // LDS anti-conflict swizzle

struct PMask { int m[2][9]; };
constexpr PMask make_pmask() {
    PMask pm{};
    for (int bd = 0; bd < 2; ++bd)
        for (int q = 0; q < 9; ++q) {
            const int img = pf(bd, 1 << q);
            for (int p = 0; p < 9; ++p)
                if ((img >> p) & 1) pm.m[bd][p] |= 1 << q;
        }
    return pm;
}
constexpr PMask PM = make_pmask();

struct T3Tab { int laneBase[2][6]; int regPart[2][8]; };
constexpr T3Tab make_t3() {
    T3Tab t{};
    for (int l = 0; l < 2; ++l) {
        for (int b = 0; b < 6; ++b) t.laneBase[l][b] = sg(pf(l, 1 << b));
        for (int g = 0; g < 8; ++g) t.regPart [l][g] = sg(pf(l, g << 6));
    }
    return t;
}
constexpr T3Tab T3T = make_t3();

constexpr int sgk3(int k) { return (k << 3) ^ (k >> 1); }   // sg(k<<3)
constexpr int sgk6(int k) { return (k << 6) ^ (k << 2); }   // sg(k<<6)

#define PI_F    3.14159265358979323846f
#define INV2PI  0.15915494309189535f

static __device__ inline unsigned pack_rn(float x, float y) {
    const __half2 h = __floats2half2_rn(x, y);
    return *(const unsigned*)&h;
}

// ws layout (float/u32 units):
//   [0..27)       gates: 27 u32 = half2{c,s}
//   [64..576)     D0h: 512 u32 = half2{dx,dy}  boundary 1->2
//   [576..1088)   D1h: 512 u32                 boundary 2->3
//   [1088..2112)  PH : 512 v2f (fp32) init-state phase
__global__ __launch_bounds__(512) void qtab_kernel(
        const float* __restrict__ wt, float* __restrict__ ws) {
    const int j = threadIdx.x;             // 0..511
    unsigned* wu = (unsigned*)ws;
    if (j < 27) {
        float s, c; __sincosf(0.5f * wt[j * 3 + 1], &s, &c);
        wu[j] = pack_rn(c, s);
    }
    #pragma unroll
    for (int bd = 0; bd < 2; ++bd) {
        float alpha = 0.0f;
        #pragma unroll
        for (int p = 0; p < 9; ++p) {
            const int w = 8 - p;
            const float om = wt[(bd * 9 + w) * 3 + 2];        // omega, layer bd
            const float ph = wt[((bd + 1) * 9 + w) * 3 + 0];  // phi, layer bd+1
            alpha += ((j >> p) & 1) ? 0.5f * om : -0.5f * om;
            alpha += (__popc(j & PM.m[bd][p]) & 1) ? 0.5f * ph : -0.5f * ph;
        }
        float sn, cs; __sincosf(alpha, &sn, &cs);
        wu[64 + bd * 512 + j] = pack_rn(cs, sn);
    }
    {
        float a = 0.0f;
        #pragma unroll
        for (int p = 0; p < 9; ++p) {
            const int w = 8 - p;
            const float phi = wt[w * 3 + 0];
            a += ((j >> p) & 1) ? (0.5f * phi - 0.5f * PI_F) : (-0.5f * phi);
        }
        float sn, cs; __sincosf(a, &sn, &cs);
        ((v2f*)(ws + 1088))[j] = (v2f){cs, sn};
    }
}

// packed-fp16 real-Y gate, in-place, coeff from ONE SGPR G = half2{c(lo),s(hi)}:
//   t = -s*a1 ; a1 = c*a1 ; a1 += s*a0 ; a0 = c*a0 + t
// (out0 = c*a0 - s*a1 ; out1 = s*a0 + c*a1; re/im packed as lo/hi half)
#define APPLY_GATE(G, KB)                                                     \
    {                                                                         \
        _Pragma("unroll")                                                     \
        for (int k0 = 0; k0 < 8; ++k0) if (!(k0 & (KB))) {                    \
            const int k1 = k0 | (KB);                                         \
            unsigned t;                                                       \
            asm("v_pk_mul_f16 %0, %1, %2 op_sel:[0,1] op_sel_hi:[1,1] "       \
                "neg_lo:[0,1] neg_hi:[0,1]"                                   \
                : "=v"(t) : "v"(a[k1]), "s"(G));        /* t = -s*a1 */       \
            asm("v_pk_mul_f16 %0, %0, %1 op_sel:[0,0] op_sel_hi:[1,0]"        \
                : "+v"(a[k1]) : "s"(G));                /* a1 = c*a1 */       \
            asm("v_pk_fma_f16 %0, %1, %2, %0 op_sel:[0,1,0] op_sel_hi:[1,1,1]"\
                : "+v"(a[k1]) : "v"(a[k0]), "s"(G));    /* a1 += s*a0 */      \
            asm("v_pk_fma_f16 %0, %0, %1, %2 op_sel:[0,0,0] op_sel_hi:[1,0,1]"\
                : "+v"(a[k0]) : "s"(G), "v"(t));        /* a0 = c*a0+t */     \
        }                                                                     \
    }

__global__ __launch_bounds__(256) void qsim_kernel(
        const float* __restrict__ x,       // (batch, 9)
        const float* __restrict__ tab,     // ws tables
        float* __restrict__ out,           // (batch, 9)
        int batch) {
    __shared__ unsigned st[4][512];        // per-wave half2 staging (8 KiB)

    const int tid  = threadIdx.x;
    const int wv   = tid >> 6;
    const int lane = tid & 63;
    const int b    = blockIdx.x * 4 + wv;
    if (b >= batch) return;
    const int bu   = __builtin_amdgcn_readfirstlane(b);   // wave-uniform

    unsigned* __restrict__ S = st[wv];
    const unsigned* __restrict__ tu = (const unsigned*)tab;
    const unsigned* __restrict__ D0 = tu + 64;
    const unsigned* __restrict__ D1 = tu + 576;
    const v2f*     __restrict__ PH = (const v2f*)(tab + 1088);

    // ---- init: magnitudes via HW trig (revolutions), phase from table ----
    float cx[9], sx[9];
    #pragma unroll
    for (int w = 0; w < 9; ++w) {
        const float rev = x[bu * 9 + w] * (0.5f * INV2PI);
        sx[w] = __builtin_amdgcn_sinf(rev);
        cx[w] = __builtin_amdgcn_cosf(rev);
    }
    float P = 1.0f;
    #pragma unroll
    for (int w = 0; w < 6; ++w)
        P *= ((lane >> (5 - w)) & 1) ? sx[w] : cx[w];

    unsigned a[8];
    #pragma unroll
    for (int k = 0; k < 8; ++k) {
        const float m = P * ((k & 4) ? sx[6] : cx[6])
                          * ((k & 2) ? sx[7] : cx[7])
                          * ((k & 1) ? sx[8] : cx[8]);
        const v2f ph = PH[(lane << 3) | k];
        a[k] = pack_rn(ph.x * m, ph.y * m);
    }

    // ---- swizzled address bases ----
    const int baseA = (lane << 3) ^ (lane >> 1);            // sg(L<<3)
    const int hB    = ((lane & 0x38) << 3) | (lane & 7);
    const int baseB = hB ^ (hB >> 4);
    const int baseC = lane ^ (lane >> 4);
    int t3b[2];
    #pragma unroll
    for (int l = 0; l < 2; ++l) {
        int v = 0;
        #pragma unroll
        for (int bb = 0; bb < 6; ++bb)
            v ^= ((lane >> bb) & 1) ? T3T.laneBase[l][bb] : 0;
        t3b[l] = v;
    }

    // ---- 3 layers of 9 packed-fp16 real-Ry gates, b32 LDS layout cycling ----
    #pragma unroll
    for (int l = 0; l < 3; ++l) {
        // this layer's 9 half2{c,s} coeffs -> 9 SGPRs, one wait
        unsigned g[9];
        #pragma unroll
        for (int q = 0; q < 9; ++q) g[q] = tu[l * 9 + q];

        APPLY_GATE(g[6], 4);   // layout A: reg bits = qubits 6,7,8
        APPLY_GATE(g[7], 2);
        APPLY_GATE(g[8], 1);

        #pragma unroll
        for (int k = 0; k < 8; ++k) S[baseA ^ k] = a[k];
        #pragma unroll
        for (int k = 0; k < 8; ++k) a[k] = S[baseB ^ sgk3(k)];

        APPLY_GATE(g[3], 4);   // layout B: reg bits = qubits 3,4,5
        APPLY_GATE(g[4], 2);
        APPLY_GATE(g[5], 1);

        #pragma unroll
        for (int k = 0; k < 8; ++k) S[baseB ^ sgk3(k)] = a[k];
        #pragma unroll
        for (int k = 0; k < 8; ++k) a[k] = S[baseC ^ sgk6(k)];

        APPLY_GATE(g[0], 4);   // layout C: reg bits = qubits 0,1,2
        APPLY_GATE(g[1], 2);
        APPLY_GATE(g[2], 1);

        if (l < 2) {
            // packed-fp16 boundary cmul: a' = a * d, d = half2{dx,dy}
            const unsigned* __restrict__ D = (l == 0) ? D0 : D1;
            #pragma unroll
            for (int k = 0; k < 8; ++k) {
                const unsigned d = D[(k << 6) | lane];
                unsigned t;
                asm("v_pk_mul_f16 %0, %1, %2 op_sel:[1,1] op_sel_hi:[0,1] "
                    "neg_lo:[0,1]"
                    : "=v"(t) : "v"(a[k]), "v"(d));  // {-dy*im, dy*re}
                asm("v_pk_fma_f16 %0, %1, %2, %3 op_sel:[0,0,0] op_sel_hi:[1,0,1]"
                    : "=v"(a[k]) : "v"(a[k]), "v"(d), "v"(t));
            }
            // T3: C -> A with the CNOT-ring permutation folded in
            #pragma unroll
            for (int k = 0; k < 8; ++k)
                S[t3b[l] ^ T3T.regPart[l][k]] = a[k];
            #pragma unroll
            for (int k = 0; k < 8; ++k) a[k] = S[baseA ^ k];
        }
    }

    // ---- epilogue (fp32): probs, packed signed accumulation, FWHT ----
    float A0 = 0.f, A1 = 0.f, A2 = 0.f, A3 = 0.f;
    #pragma unroll
    for (int k = 0; k < 8; ++k) {
        const __half2 h = *(const __half2*)&a[k];
        const float2 f = __half22float2(h);
        const float p = f.x * f.x + f.y * f.y;
        A0 += p;
        A1 += (k & 4) ? -p : p;
        A2 += (k & 2) ? -p : p;
        A3 += (k & 1) ? -p : p;
    }
    v2f F01 = (v2f){A0, A1};   // {F_S, F_U4}
    v2f F23 = (v2f){A2, A3};   // {F_U2, F_U1}

    // 6-step FWHT butterfly: lane m ends with Sum_j (-1)^popc(j&m) F(j)
    #pragma unroll
    for (int d = 1; d < 64; d <<= 1) {
        const float sg1 = (lane & d) ? -1.0f : 1.0f;
        const v2f sgn = (v2f){sg1, sg1};
        v2f p01, p23;
        p01.x = __shfl_xor(F01.x, d, 64);  p01.y = __shfl_xor(F01.y, d, 64);
        p23.x = __shfl_xor(F23.x, d, 64);  p23.y = __shfl_xor(F23.y, d, 64);
        F01 = F01 * sgn + p01;
        F23 = F23 * sgn + p23;
    }
    // gather the 9 needed Walsh coefficients via LDS (reuse staging as float)
    float* Sf = (float*)S;
    Sf[2 * lane]           = F01.x;
    Sf[2 * lane + 1]       = F01.y;
    Sf[128 + 2 * lane]     = F23.x;
    Sf[128 + 2 * lane + 1] = F23.y;
    if (lane < 9) {
        const int idx = (lane == 0) ? 72  : (lane == 1) ? 36  : (lane == 2) ? 18
                      : (lane == 3) ? 65  : (lane == 4) ? 160 : (lane == 5) ? 145
                      : (lane == 6) ? 73  : (lane == 7) ? 164 : 147;
        out[bu * 9 + lane] = Sf[idx];
    }
}

extern "C" void kernel_launch(void* const* d_in, const int* in_sizes, int n_in,
                              void* d_out, int out_size, void* d_ws, size_t ws_size,
                              hipStream_t stream) {
    const float* x  = (const float*)d_in[0];   // (32768, 9) fp32
    const float* wt = (const float*)d_in[1];   // (3, 9, 3) fp32
    float* out = (float*)d_out;                // (32768, 9) fp32
    const int batch = in_sizes[0] / 9;
    float* ws = (float*)d_ws;                  // 2112 floats = 8.4 KB used

    hipLaunchKernelGGL(qtab_kernel, dim3(1), dim3(512), 0, stream, wt, ws);
    hipLaunchKernelGGL(qsim_kernel, dim3((batch + 3) / 4), dim3(256), 0, stream,
                       x, ws, out, batch);
}

// Round 11
// 99.273 us; speedup vs baseline: 1.1052x; 1.0409x over previous
//
#include <hip/hip_runtime.h>
#include <hip/hip_fp16.h>

// ---------------------------------------------------------------------------
// 9-qubit batched state-vector simulator, v11.
// v10 fp16 amplitude pipeline + redesigned per-transition LDS swizzles:
//   each round-trip gets its own bit-permutation sigma chosen so that
//    - READS are contiguous (reg-bits -> addr bits 0..2): 2x ds_read_b128
//    - WRITES are additive (reg-bits -> addr bits 5..7): ds_write_b32 with
//      immediate offsets k<<5 off one precomputed lane base (no addr VALU)
//    - write sets hit 2 lanes/bank (lane-bits cover addr bits 0..4) = free
//   T3 (CNOT-fused) sigma found per layer by constexpr search over 720 perms.
// Epilogue: v_dot2_f32_f16 accumulation. Init: binary-tree magnitudes.
// Gates / boundary diag: v10's validated VOP3P asm, unchanged.
// ---------------------------------------------------------------------------

typedef float v2f __attribute__((ext_vector_type(2)));
typedef _Float16 v2h __attribute__((ext_vector_type(2)));

constexpr int pf(int l, int i) {        // forward CNOT-ring basis map, layer l
    const int r = l + 1; int j = i;
    for (int c = 0; c < 9; ++c) {
        const int bit = (j >> (8 - c)) & 1;
        const int t = (c + r) % 9;
        j ^= bit << (8 - t);
    }
    return j;
}

struct PMask { int m[2][9]; };
constexpr PMask make_pmask() {
    PMask pm{};
    for (int bd = 0; bd < 2; ++bd)
        for (int q = 0; q < 9; ++q) {
            const int img = pf(bd, 1 << q);
            for (int p = 0; p < 9; ++p)
                if ((img >> p) & 1) pm.m[bd][p] |= 1 << q;
        }
    return pm;
}
constexpr PMask PM = make_pmask();

// ---- sigma3 per boundary: img[b] = dest bit of source bit b; bits 0..2 id ----
struct Sig3 {
    int wbasis[6];   // sigma3(pf(l, 1<<b))        b = lane bit (C layout)
    int koff[8];     // sigma3(pf(l, k<<6))        k = reg index (C layout)
    int rimg[6];     // dest bit of source bit 3+b (for A-read base)
};
constexpr Sig3 make_sig3(int l) {
    Sig3 out{};
    for (int limit = 2; limit <= 64; limit *= 2) {
        for (int idx = 0; idx < 720; ++idx) {
            int pool[6] = {3, 4, 5, 6, 7, 8};
            int perm[6] = {};
            int f = idx;
            const int fact[6] = {120, 24, 6, 2, 1, 1};
            int n = 6;
            for (int pos = 0; pos < 6; ++pos) {
                const int sel = f / fact[pos]; f %= fact[pos];
                perm[pos] = pool[sel];
                for (int m2 = sel; m2 + 1 < n; ++m2) pool[m2] = pool[m2 + 1];
                --n;
            }
            int img[9] = {0, 1, 2, perm[0], perm[1], perm[2],
                          perm[3], perm[4], perm[5]};
            int cnt[32] = {};
            bool ok = true;
            for (int L = 0; L < 64 && ok; ++L) {
                const int j = pf(l, L);
                int addr = 0;
                for (int bb = 0; bb < 9; ++bb)
                    if ((j >> bb) & 1) addr ^= 1 << img[bb];
                if (++cnt[addr & 31] > limit) ok = false;
            }
            if (ok) {
                for (int b2 = 0; b2 < 6; ++b2) {
                    const int j = pf(l, 1 << b2); int v = 0;
                    for (int bb = 0; bb < 9; ++bb)
                        if ((j >> bb) & 1) v ^= 1 << img[bb];
                    out.wbasis[b2] = v;
                }
                for (int k = 0; k < 8; ++k) {
                    const int j = pf(l, k << 6); int v = 0;
                    for (int bb = 0; bb < 9; ++bb)
                        if ((j >> bb) & 1) v ^= 1 << img[bb];
                    out.koff[k] = v;
                }
                for (int b2 = 0; b2 < 6; ++b2) out.rimg[b2] = img[3 + b2];
                return out;
            }
        }
    }
    return out;
}
constexpr Sig3 S3_0 = make_sig3(0);
constexpr Sig3 S3_1 = make_sig3(1);

#define PI_F    3.14159265358979323846f
#define INV2PI  0.15915494309189535f

static __device__ inline unsigned pack_rn(float x, float y) {
    const __half2 h = __floats2half2_rn(x, y);
    return *(const unsigned*)&h;
}

// ws layout (u32/float units):
//   [0..27)       gates: 27 u32 = half2{c,s}
//   [64..576)     D0h: 512 u32 = half2{dx,dy}  boundary 1->2
//   [576..1088)   D1h: 512 u32                 boundary 2->3
//   [1088..2112)  PH : 512 v2f (fp32) init-state phase
__global__ __launch_bounds__(512) void qtab_kernel(
        const float* __restrict__ wt, float* __restrict__ ws) {
    const int j = threadIdx.x;             // 0..511
    unsigned* wu = (unsigned*)ws;
    if (j < 27) {
        float s, c; __sincosf(0.5f * wt[j * 3 + 1], &s, &c);
        wu[j] = pack_rn(c, s);
    }
    #pragma unroll
    for (int bd = 0; bd < 2; ++bd) {
        float alpha = 0.0f;
        #pragma unroll
        for (int p = 0; p < 9; ++p) {
            const int w = 8 - p;
            const float om = wt[(bd * 9 + w) * 3 + 2];        // omega, layer bd
            const float ph = wt[((bd + 1) * 9 + w) * 3 + 0];  // phi, layer bd+1
            alpha += ((j >> p) & 1) ? 0.5f * om : -0.5f * om;
            alpha += (__popc(j & PM.m[bd][p]) & 1) ? 0.5f * ph : -0.5f * ph;
        }
        float sn, cs; __sincosf(alpha, &sn, &cs);
        wu[64 + bd * 512 + j] = pack_rn(cs, sn);
    }
    {
        float a = 0.0f;
        #pragma unroll
        for (int p = 0; p < 9; ++p) {
            const int w = 8 - p;
            const float phi = wt[w * 3 + 0];
            a += ((j >> p) & 1) ? (0.5f * phi - 0.5f * PI_F) : (-0.5f * phi);
        }
        float sn, cs; __sincosf(a, &sn, &cs);
        ((v2f*)(ws + 1088))[j] = (v2f){cs, sn};
    }
}

// packed-fp16 real-Y gate, in-place, coeff from ONE SGPR G = half2{c(lo),s(hi)}
#define APPLY_GATE(G, KB)                                                     \
    {                                                                         \
        _Pragma("unroll")                                                     \
        for (int k0 = 0; k0 < 8; ++k0) if (!(k0 & (KB))) {                    \
            const int k1 = k0 | (KB);                                         \
            unsigned t;                                                       \
            asm("v_pk_mul_f16 %0, %1, %2 op_sel:[0,1] op_sel_hi:[1,1] "       \
                "neg_lo:[0,1] neg_hi:[0,1]"                                   \
                : "=v"(t) : "v"(a[k1]), "s"(G));        /* t = -s*a1 */       \
            asm("v_pk_mul_f16 %0, %0, %1 op_sel:[0,0] op_sel_hi:[1,0]"        \
                : "+v"(a[k1]) : "s"(G));                /* a1 = c*a1 */       \
            asm("v_pk_fma_f16 %0, %1, %2, %0 op_sel:[0,1,0] op_sel_hi:[1,1,1]"\
                : "+v"(a[k1]) : "v"(a[k0]), "s"(G));    /* a1 += s*a0 */      \
            asm("v_pk_fma_f16 %0, %0, %1, %2 op_sel:[0,0,0] op_sel_hi:[1,0,1]"\
                : "+v"(a[k0]) : "s"(G), "v"(t));        /* a0 = c*a0+t */     \
        }                                                                     \
    }

__global__ __launch_bounds__(256) void qsim_kernel(
        const float* __restrict__ x,       // (batch, 9)
        const float* __restrict__ tab,     // ws tables
        float* __restrict__ out,           // (batch, 9)
        int batch) {
    __shared__ uint4 st4[4][128];          // per-wave staging (8 KiB total)

    const int tid  = threadIdx.x;
    const int wv   = tid >> 6;
    const int lane = tid & 63;
    const int b    = blockIdx.x * 4 + wv;
    if (b >= batch) return;
    const int bu   = __builtin_amdgcn_readfirstlane(b);   // wave-uniform

    unsigned* __restrict__ S  = (unsigned*)st4[wv];
    const uint4* __restrict__ S4 = st4[wv];
    const unsigned* __restrict__ tu = (const unsigned*)tab;
    const unsigned* __restrict__ D0 = tu + 64;
    const unsigned* __restrict__ D1 = tu + 576;
    const float4*  __restrict__ PH4 = (const float4*)(tab + 1088);

    // ---- init: magnitudes via HW trig + binary tree, phase from table ----
    float cx[9], sx[9];
    #pragma unroll
    for (int w = 0; w < 9; ++w) {
        const float rev = x[bu * 9 + w] * (0.5f * INV2PI);
        sx[w] = __builtin_amdgcn_sinf(rev);
        cx[w] = __builtin_amdgcn_cosf(rev);
    }
    float P = 1.0f;
    #pragma unroll
    for (int w = 0; w < 6; ++w)
        P *= ((lane >> (5 - w)) & 1) ? sx[w] : cx[w];

    // binary tree over qubits 6,7,8 (k bits 2,1,0)
    float mk[8];
    {
        const float m0 = P * cx[6],  m1 = P * sx[6];
        const float m00 = m0 * cx[7], m01 = m0 * sx[7];
        const float m10 = m1 * cx[7], m11 = m1 * sx[7];
        mk[0] = m00 * cx[8]; mk[1] = m00 * sx[8];
        mk[2] = m01 * cx[8]; mk[3] = m01 * sx[8];
        mk[4] = m10 * cx[8]; mk[5] = m10 * sx[8];
        mk[6] = m11 * cx[8]; mk[7] = m11 * sx[8];
    }
    unsigned a[8];
    #pragma unroll
    for (int j2 = 0; j2 < 4; ++j2) {
        const float4 ph = PH4[(lane << 2) + j2];
        a[2 * j2]     = pack_rn(ph.x * mk[2 * j2],     ph.y * mk[2 * j2]);
        a[2 * j2 + 1] = pack_rn(ph.z * mk[2 * j2 + 1], ph.w * mk[2 * j2 + 1]);
    }

    // ---- per-transition address bases (bit-permutation swizzles) ----
    // sigma1: [5,6,7, 0,1,2, 3,4,8]   A-write additive k<<5 / B-read contig
    const int wb1 = (lane & 31) | ((lane & 32) << 3);
    const int rb1 = ((lane & 7) << 5) | (lane & 0x18) | ((lane & 32) << 3);
    // sigma2: [3,4,8, 5,6,7, 0,1,2]   B-write additive k<<5 / C-read contig
    const int wb2 = ((lane >> 3) & 7) | ((lane & 3) << 3) | ((lane & 4) << 6);
    const int rb2 = ((lane & 3) << 3) | ((lane & 4) << 6) | ((lane & 0x38) << 2);
    // sigma3 per boundary: T3-write XOR base + A-read contig base
    int t3b[2], rb3[2];
    #pragma unroll
    for (int l = 0; l < 2; ++l) {
        int tb = 0, rb = 0;
        #pragma unroll
        for (int bb = 0; bb < 6; ++bb) {
            const int on = (lane >> bb) & 1;
            tb ^= on ? (l ? S3_1.wbasis[bb] : S3_0.wbasis[bb]) : 0;
            rb ^= on ? (1 << (l ? S3_1.rimg[bb] : S3_0.rimg[bb])) : 0;
        }
        t3b[l] = tb; rb3[l] = rb;
    }

    // ---- 3 layers of 9 packed-fp16 real-Ry gates ----
    #pragma unroll
    for (int l = 0; l < 3; ++l) {
        unsigned g[9];
        #pragma unroll
        for (int q = 0; q < 9; ++q) g[q] = tu[l * 9 + q];

        APPLY_GATE(g[6], 4);   // layout A: reg bits = qubits 6,7,8
        APPLY_GATE(g[7], 2);
        APPLY_GATE(g[8], 1);

        // T1: A -> B   (writes: base + k<<5 imm; reads: 2x b128)
        #pragma unroll
        for (int k = 0; k < 8; ++k) S[wb1 + (k << 5)] = a[k];
        {
            const uint4 r0 = S4[(rb1 >> 2)];
            const uint4 r1 = S4[(rb1 >> 2) + 1];
            a[0] = r0.x; a[1] = r0.y; a[2] = r0.z; a[3] = r0.w;
            a[4] = r1.x; a[5] = r1.y; a[6] = r1.z; a[7] = r1.w;
        }

        APPLY_GATE(g[3], 4);   // layout B: reg bits = qubits 3,4,5
        APPLY_GATE(g[4], 2);
        APPLY_GATE(g[5], 1);

        // T2: B -> C
        #pragma unroll
        for (int k = 0; k < 8; ++k) S[wb2 + (k << 5)] = a[k];
        {
            const uint4 r0 = S4[(rb2 >> 2)];
            const uint4 r1 = S4[(rb2 >> 2) + 1];
            a[0] = r0.x; a[1] = r0.y; a[2] = r0.z; a[3] = r0.w;
            a[4] = r1.x; a[5] = r1.y; a[6] = r1.z; a[7] = r1.w;
        }

        APPLY_GATE(g[0], 4);   // layout C: reg bits = qubits 0,1,2
        APPLY_GATE(g[1], 2);
        APPLY_GATE(g[2], 1);

        if (l < 2) {
            // packed-fp16 boundary cmul: a' = a * d, d = half2{dx,dy}
            const unsigned* __restrict__ D = (l == 0) ? D0 : D1;
            #pragma unroll
            for (int k = 0; k < 8; ++k) {
                const unsigned d = D[(k << 6) | lane];
                unsigned t;
                asm("v_pk_mul_f16 %0, %1, %2 op_sel:[1,1] op_sel_hi:[0,1] "
                    "neg_lo:[0,1]"
                    : "=v"(t) : "v"(a[k]), "v"(d));
                asm("v_pk_fma_f16 %0, %1, %2, %3 op_sel:[0,0,0] op_sel_hi:[1,0,1]"
                    : "=v"(a[k]) : "v"(a[k]), "v"(d), "v"(t));
            }
            // T3: C -> A with CNOT perm folded (XOR scatter, b128 gather)
            #pragma unroll
            for (int k = 0; k < 8; ++k)
                S[t3b[l] ^ (l ? S3_1.koff[k] : S3_0.koff[k])] = a[k];
            {
                const uint4 r0 = S4[(rb3[l] >> 2)];
                const uint4 r1 = S4[(rb3[l] >> 2) + 1];
                a[0] = r0.x; a[1] = r0.y; a[2] = r0.z; a[3] = r0.w;
                a[4] = r1.x; a[5] = r1.y; a[6] = r1.z; a[7] = r1.w;
            }
        }
    }

    // ---- epilogue: dot2 accumulation + FWHT ----
    float A0 = 0.f, A1 = 0.f, A2 = 0.f, A3 = 0.f;
    #pragma unroll
    for (int k = 0; k < 8; ++k) {
#if __has_builtin(__builtin_amdgcn_fdot2)
        v2h h, hn;
        { unsigned u = a[k];               h = *(const v2h*)&u; }
        { unsigned un = a[k] ^ 0x80008000u; hn = *(const v2h*)&un; }
        A0 = __builtin_amdgcn_fdot2(h, h, A0, false);
        A1 = __builtin_amdgcn_fdot2(h, (k & 4) ? hn : h, A1, false);
        A2 = __builtin_amdgcn_fdot2(h, (k & 2) ? hn : h, A2, false);
        A3 = __builtin_amdgcn_fdot2(h, (k & 1) ? hn : h, A3, false);
#else
        const __half2 h = *(const __half2*)&a[k];
        const float2 f = __half22float2(h);
        const float p = f.x * f.x + f.y * f.y;
        A0 += p;
        A1 += (k & 4) ? -p : p;
        A2 += (k & 2) ? -p : p;
        A3 += (k & 1) ? -p : p;
#endif
    }
    v2f F01 = (v2f){A0, A1};   // {F_S, F_U4}
    v2f F23 = (v2f){A2, A3};   // {F_U2, F_U1}

    #pragma unroll
    for (int d = 1; d < 64; d <<= 1) {
        const float sg1 = (lane & d) ? -1.0f : 1.0f;
        const v2f sgn = (v2f){sg1, sg1};
        v2f p01, p23;
        p01.x = __shfl_xor(F01.x, d, 64);  p01.y = __shfl_xor(F01.y, d, 64);
        p23.x = __shfl_xor(F23.x, d, 64);  p23.y = __shfl_xor(F23.y, d, 64);
        F01 = F01 * sgn + p01;
        F23 = F23 * sgn + p23;
    }
    float* Sf = (float*)S;
    Sf[2 * lane]           = F01.x;
    Sf[2 * lane + 1]       = F01.y;
    Sf[128 + 2 * lane]     = F23.x;
    Sf[128 + 2 * lane + 1] = F23.y;
    if (lane < 9) {
        const int idx = (lane == 0) ? 72  : (lane == 1) ? 36  : (lane == 2) ? 18
                      : (lane == 3) ? 65  : (lane == 4) ? 160 : (lane == 5) ? 145
                      : (lane == 6) ? 73  : (lane == 7) ? 164 : 147;
        out[bu * 9 + lane] = Sf[idx];
    }
}

extern "C" void kernel_launch(void* const* d_in, const int* in_sizes, int n_in,
                              void* d_out, int out_size, void* d_ws, size_t ws_size,
                              hipStream_t stream) {
    const float* x  = (const float*)d_in[0];   // (32768, 9) fp32
    const float* wt = (const float*)d_in[1];   // (3, 9, 3) fp32
    float* out = (float*)d_out;                // (32768, 9) fp32
    const int batch = in_sizes[0] / 9;
    float* ws = (float*)d_ws;                  // 2112 floats = 8.4 KB used

    hipLaunchKernelGGL(qtab_kernel, dim3(1), dim3(512), 0, stream, wt, ws);
    hipLaunchKernelGGL(qsim_kernel, dim3((batch + 3) / 4), dim3(256), 0, stream,
                       x, ws, out, batch);
}